// Round 1
// baseline (394.885 us; speedup 1.0000x reference)
//
#include <hip/hip_runtime.h>

typedef __attribute__((ext_vector_type(8))) short short8;
typedef __attribute__((ext_vector_type(4))) short short4v;
typedef __attribute__((ext_vector_type(4))) float f32x4;

__device__ __forceinline__ unsigned short f2bf(float f) {
  union { float f; unsigned u; } v; v.f = f;
  unsigned u = v.u;
  unsigned r = (u + 0x7FFFu + ((u >> 16) & 1u)) >> 16;
  return (unsigned short)r;
}

// ---------------------------------------------------------------------------
// Weight prep: Wq/Wv [16][1024][64] f32 -> Bt [1024][1024] bf16, Bt[h*64+j][d]
// ---------------------------------------------------------------------------
__global__ __launch_bounds__(256)
void wtrans_k(const float* __restrict__ W, unsigned short* __restrict__ Bt) {
  __shared__ float tile[64 * 65];
  const int h  = blockIdx.x >> 4;
  const int d0 = (blockIdx.x & 15) * 64;
  const int tid = threadIdx.x;
#pragma unroll
  for (int i = 0; i < 16; ++i) {
    int e = i * 256 + tid;
    int r = e >> 6, c = e & 63;
    tile[r * 65 + c] = W[(size_t)h * 65536 + (size_t)(d0 + r) * 64 + c];
  }
  __syncthreads();
#pragma unroll
  for (int i = 0; i < 16; ++i) {
    int e = i * 256 + tid;
    int jj = e >> 6, dd = e & 63;
    Bt[(size_t)(h * 64 + jj) * 1024 + d0 + dd] = f2bf(tile[dd * 65 + jj]);
  }
}

// Wo [1024][1024] f32 -> bf16 (already B^T layout: out = concat @ Wo^T)
__global__ __launch_bounds__(256)
void wo_conv_k(const float* __restrict__ Wo, unsigned short* __restrict__ BoT) {
  size_t t = (size_t)blockIdx.x * 256 + threadIdx.x;
  float4 f = *(const float4*)(Wo + t * 4);
  short4v v;
  v[0] = (short)f2bf(f.x); v[1] = (short)f2bf(f.y);
  v[2] = (short)f2bf(f.z); v[3] = (short)f2bf(f.w);
  *(short4v*)((short*)BoT + t * 4) = v;
}

// ---------------------------------------------------------------------------
// GEMM: C[m][n] = sum_k A[m][k] * Bt[n][k];  M=4096, N=1024, K=1024
// AF32: A is f32 (converted to bf16 during staging), else A is bf16.
// EPI 0: dst bf16 [b][h][s][hd]   (q / k)
// EPI 1: dst bf16 [b][h][hd][s]   (v transposed)
// EPI 2: dst f32  [m][n] + bias[n] (final output)
// ---------------------------------------------------------------------------
template<bool AF32, int EPI>
__global__ __launch_bounds__(256)
void gemm_k(const void* __restrict__ Ap, const short* __restrict__ Bt,
            void* __restrict__ Cp, const float* __restrict__ bias) {
  constexpr int K = 1024;
  __shared__ short As[128 * 32];
  __shared__ short Bs[128 * 32];
  const int tid = threadIdx.x;
  const int l = tid & 63;
  const int w = tid >> 6;
  const int wr = w >> 1, wc = w & 1;
  const int bid = blockIdx.x;
  const int bm = bid >> 3, bn = bid & 7;

  f32x4 acc[4][4] = {};
  const int c0 = tid * 2;

  for (int k0 = 0; k0 < K; k0 += 32) {
    __syncthreads();
    if (AF32) {
      const float* A = (const float*)Ap;
#pragma unroll
      for (int i = 0; i < 2; ++i) {
        int c = c0 + i;
        int row = c >> 2, ko = (c & 3) * 8;
        const float* src = A + (size_t)(bm * 128 + row) * K + k0 + ko;
        float4 f0 = *(const float4*)src;
        float4 f1 = *(const float4*)(src + 4);
        short8 v;
        v[0] = (short)f2bf(f0.x); v[1] = (short)f2bf(f0.y);
        v[2] = (short)f2bf(f0.z); v[3] = (short)f2bf(f0.w);
        v[4] = (short)f2bf(f1.x); v[5] = (short)f2bf(f1.y);
        v[6] = (short)f2bf(f1.z); v[7] = (short)f2bf(f1.w);
        *(short8*)&As[row * 32 + ko] = v;
      }
    } else {
      const short* A = (const short*)Ap;
#pragma unroll
      for (int i = 0; i < 2; ++i) {
        int c = c0 + i;
        int row = c >> 2, ko = (c & 3) * 8;
        *(short8*)&As[row * 32 + ko] =
            *(const short8*)(A + (size_t)(bm * 128 + row) * K + k0 + ko);
      }
    }
#pragma unroll
    for (int i = 0; i < 2; ++i) {
      int c = c0 + i;
      int row = c >> 2, ko = (c & 3) * 8;
      *(short8*)&Bs[row * 32 + ko] =
          *(const short8*)(Bt + (size_t)(bn * 128 + row) * K + k0 + ko);
    }
    __syncthreads();

    short8 af[4], bf[4];
#pragma unroll
    for (int mi = 0; mi < 4; ++mi)
      af[mi] = *(const short8*)&As[(wr * 64 + mi * 16 + (l & 15)) * 32 + (l >> 4) * 8];
#pragma unroll
    for (int ni = 0; ni < 4; ++ni)
      bf[ni] = *(const short8*)&Bs[(wc * 64 + ni * 16 + (l & 15)) * 32 + (l >> 4) * 8];
#pragma unroll
    for (int mi = 0; mi < 4; ++mi)
#pragma unroll
      for (int ni = 0; ni < 4; ++ni)
        acc[mi][ni] = __builtin_amdgcn_mfma_f32_16x16x32_bf16(af[mi], bf[ni], acc[mi][ni], 0, 0, 0);
  }

  const int mb = bm * 128 + wr * 64 + (l >> 4) * 4;
  const int nb = bn * 128 + wc * 64 + (l & 15);
#pragma unroll
  for (int mi = 0; mi < 4; ++mi) {
#pragma unroll
    for (int ni = 0; ni < 4; ++ni) {
#pragma unroll
      for (int j = 0; j < 4; ++j) {
        float v = acc[mi][ni][j];
        int m = mb + mi * 16 + j;
        int n = nb + ni * 16;
        if (EPI == 2) {
          ((float*)Cp)[(size_t)m * 1024 + n] = v + bias[n];
        } else {
          int b = m >> 11, s = m & 2047, h = n >> 6, hd = n & 63;
          size_t idx;
          if (EPI == 0) idx = ((size_t)((b * 16 + h) * 2048 + s)) * 64 + hd;
          else          idx = ((size_t)((b * 16 + h) * 64 + hd)) * 2048 + s;
          ((unsigned short*)Cp)[idx] = f2bf(v);
        }
      }
    }
  }
}

// ---------------------------------------------------------------------------
// Flash attention: block = (b,h,qtile of 64 rows), 4 waves x 16 rows.
// q/k: [b][h][s][64] bf16; v: [b][h][64][s] bf16 (transposed).
// Output: attn concat layout [b][s][h*64+hd] bf16.
// ---------------------------------------------------------------------------
__global__ __launch_bounds__(256)
void attn_k(const unsigned short* __restrict__ qh, const unsigned short* __restrict__ kh,
            const unsigned short* __restrict__ vT, unsigned short* __restrict__ attnc) {
  __shared__ short Pl[4][16 * 40];   // per-wave P tile, rows padded to 40 bf16
  const int bid = blockIdx.x;
  const int qt = bid & 31;
  const int h = (bid >> 5) & 15;
  const int b = bid >> 9;
  const int tid = threadIdx.x;
  const int l = tid & 63;
  const int w = tid >> 6;
  const int lg = l >> 4;
  const int lc = l & 15;

  const unsigned short* qb = qh + (size_t)((b * 16 + h) * 2048) * 64;
  const unsigned short* kb = kh + (size_t)((b * 16 + h) * 2048) * 64;
  const unsigned short* vb = vT + (size_t)((b * 16 + h) * 64) * 2048;

  const int s0 = qt * 64 + w * 16;
  short8 qf0 = *(const short8*)(qb + (s0 + lc) * 64 + lg * 8);
  short8 qf1 = *(const short8*)(qb + (s0 + lc) * 64 + 32 + lg * 8);

  float m_r[4], l_r[4];
  f32x4 acco[4];
#pragma unroll
  for (int j = 0; j < 4; ++j) { m_r[j] = -1e30f; l_r[j] = 0.f; }
#pragma unroll
  for (int n = 0; n < 4; ++n) acco[n] = (f32x4){0.f, 0.f, 0.f, 0.f};

  short* pw = &Pl[w][0];
  const f32x4 zero = (f32x4){0.f, 0.f, 0.f, 0.f};

  for (int t0 = 0; t0 < 2048; t0 += 32) {
    const unsigned short* kp0 = kb + (t0 + lc) * 64 + lg * 8;
    const unsigned short* kp1 = kb + (t0 + 16 + lc) * 64 + lg * 8;
    short8 k00 = *(const short8*)(kp0);
    short8 k01 = *(const short8*)(kp0 + 32);
    short8 k10 = *(const short8*)(kp1);
    short8 k11 = *(const short8*)(kp1 + 32);

    f32x4 sa = __builtin_amdgcn_mfma_f32_16x16x32_bf16(qf0, k00, zero, 0, 0, 0);
    sa = __builtin_amdgcn_mfma_f32_16x16x32_bf16(qf1, k01, sa, 0, 0, 0);
    f32x4 sb = __builtin_amdgcn_mfma_f32_16x16x32_bf16(qf0, k10, zero, 0, 0, 0);
    sb = __builtin_amdgcn_mfma_f32_16x16x32_bf16(qf1, k11, sb, 0, 0, 0);

    float tm[4];
#pragma unroll
    for (int j = 0; j < 4; ++j) {
      sa[j] *= 0.125f; sb[j] *= 0.125f;
      tm[j] = fmaxf(sa[j], sb[j]);
    }
#pragma unroll
    for (int st = 0; st < 4; ++st)
#pragma unroll
      for (int j = 0; j < 4; ++j)
        tm[j] = fmaxf(tm[j], __shfl_xor(tm[j], 1 << st));

    float pa_[4], pb_[4], rs[4], sc[4];
#pragma unroll
    for (int j = 0; j < 4; ++j) {
      float mn = fmaxf(m_r[j], tm[j]);
      sc[j] = __expf(m_r[j] - mn);
      m_r[j] = mn;
      pa_[j] = __expf(sa[j] - mn);
      pb_[j] = __expf(sb[j] - mn);
      rs[j] = pa_[j] + pb_[j];
    }
#pragma unroll
    for (int st = 0; st < 4; ++st)
#pragma unroll
      for (int j = 0; j < 4; ++j)
        rs[j] += __shfl_xor(rs[j], 1 << st);
#pragma unroll
    for (int j = 0; j < 4; ++j) l_r[j] = l_r[j] * sc[j] + rs[j];
#pragma unroll
    for (int n = 0; n < 4; ++n)
#pragma unroll
      for (int j = 0; j < 4; ++j) acco[n][j] *= sc[j];

#pragma unroll
    for (int j = 0; j < 4; ++j) {
      int row = lg * 4 + j;
      pw[row * 40 + lc]      = (short)f2bf(pa_[j]);
      pw[row * 40 + 16 + lc] = (short)f2bf(pb_[j]);
    }
    short8 pfrag = *(const short8*)&pw[lc * 40 + lg * 8];

#pragma unroll
    for (int n = 0; n < 4; ++n) {
      short8 vf = *(const short8*)(vb + (size_t)(n * 16 + lc) * 2048 + t0 + lg * 8);
      acco[n] = __builtin_amdgcn_mfma_f32_16x16x32_bf16(pfrag, vf, acco[n], 0, 0, 0);
    }
  }

  float inv[4];
#pragma unroll
  for (int j = 0; j < 4; ++j) inv[j] = 1.0f / l_r[j];
#pragma unroll
  for (int n = 0; n < 4; ++n)
#pragma unroll
    for (int j = 0; j < 4; ++j) {
      int s = s0 + lg * 4 + j;
      int col = h * 64 + n * 16 + lc;
      attnc[(size_t)(b * 2048 + s) * 1024 + col] = f2bf(acco[n][j] * inv[j]);
    }
}

// ---------------------------------------------------------------------------
extern "C" void kernel_launch(void* const* d_in, const int* in_sizes, int n_in,
                              void* d_out, int out_size, void* d_ws, size_t ws_size,
                              hipStream_t stream) {
  const float* Q  = (const float*)d_in[0];
  const float* Kt = (const float*)d_in[1];
  const float* V  = (const float*)d_in[2];
  const float* Wq = (const float*)d_in[3];
  const float* Wv = (const float*)d_in[4];
  const float* Wo = (const float*)d_in[5];
  const float* bo = (const float*)d_in[6];
  float* out = (float*)d_out;

  char* ws = (char*)d_ws;
  unsigned short* qh   = (unsigned short*)(ws);                      // 8 MB
  unsigned short* kh   = (unsigned short*)(ws + ((size_t)8 << 20));  // 8 MB
  unsigned short* vTh  = (unsigned short*)(ws + ((size_t)16 << 20)); // 8 MB
  unsigned short* attc = (unsigned short*)(ws + ((size_t)24 << 20)); // 8 MB
  unsigned short* BqT  = (unsigned short*)(ws + ((size_t)32 << 20)); // 2 MB
  unsigned short* BvT  = (unsigned short*)(ws + ((size_t)34 << 20)); // 2 MB
  unsigned short* BoT  = (unsigned short*)(ws + ((size_t)36 << 20)); // 2 MB

  wtrans_k<<<256, 256, 0, stream>>>(Wq, BqT);
  wtrans_k<<<256, 256, 0, stream>>>(Wv, BvT);
  wo_conv_k<<<1024, 256, 0, stream>>>(Wo, BoT);

  gemm_k<true, 0><<<256, 256, 0, stream>>>(Q,  (const short*)BqT, qh, nullptr);
  gemm_k<true, 0><<<256, 256, 0, stream>>>(Kt, (const short*)BqT, kh, nullptr);
  gemm_k<true, 1><<<256, 256, 0, stream>>>(V,  (const short*)BvT, vTh, nullptr);

  attn_k<<<1024, 256, 0, stream>>>(qh, kh, vTh, attc);

  gemm_k<false, 2><<<256, 256, 0, stream>>>(attc, (const short*)BoT, out, bo);
}

// Round 2
// 388.509 us; speedup vs baseline: 1.0164x; 1.0164x over previous
//
#include <hip/hip_runtime.h>

typedef __attribute__((ext_vector_type(8))) short short8;
typedef __attribute__((ext_vector_type(4))) short short4v;
typedef __attribute__((ext_vector_type(4))) float f32x4;

__device__ __forceinline__ unsigned short f2bf(float f) {
  union { float f; unsigned u; } v; v.f = f;
  unsigned u = v.u;
  unsigned r = (u + 0x7FFFu + ((u >> 16) & 1u)) >> 16;
  return (unsigned short)r;
}

#if __has_builtin(__builtin_amdgcn_exp2f)
__device__ __forceinline__ float exp2_fast(float x) { return __builtin_amdgcn_exp2f(x); }
#else
__device__ __forceinline__ float exp2_fast(float x) { return __expf(x * 0.69314718056f); }
#endif

// q pre-scale: 1/sqrt(64) * log2(e) so scores are already in exp2 domain.
#define QSCALE 0.1803368801111f

// ---------------------------------------------------------------------------
// Weight prep: Wq/Wv [16][1024][64] f32 -> Bt [1024][1024] bf16, Bt[h*64+j][d]
// ---------------------------------------------------------------------------
__global__ __launch_bounds__(256)
void wtrans_k(const float* __restrict__ W, unsigned short* __restrict__ Bt) {
  __shared__ float tile[64 * 65];
  const int h  = blockIdx.x >> 4;
  const int d0 = (blockIdx.x & 15) * 64;
  const int tid = threadIdx.x;
#pragma unroll
  for (int i = 0; i < 16; ++i) {
    int e = i * 256 + tid;
    int r = e >> 6, c = e & 63;
    tile[r * 65 + c] = W[(size_t)h * 65536 + (size_t)(d0 + r) * 64 + c];
  }
  __syncthreads();
#pragma unroll
  for (int i = 0; i < 16; ++i) {
    int e = i * 256 + tid;
    int jj = e >> 6, dd = e & 63;
    Bt[(size_t)(h * 64 + jj) * 1024 + d0 + dd] = f2bf(tile[dd * 65 + jj]);
  }
}

// Wo [1024][1024] f32 -> bf16 (already B^T layout: out = concat @ Wo^T)
__global__ __launch_bounds__(256)
void wo_conv_k(const float* __restrict__ Wo, unsigned short* __restrict__ BoT) {
  size_t t = (size_t)blockIdx.x * 256 + threadIdx.x;
  float4 f = *(const float4*)(Wo + t * 4);
  short4v v;
  v[0] = (short)f2bf(f.x); v[1] = (short)f2bf(f.y);
  v[2] = (short)f2bf(f.z); v[3] = (short)f2bf(f.w);
  *(short4v*)((short*)BoT + t * 4) = v;
}

// ---------------------------------------------------------------------------
// GEMM: C[m][n] = sum_k A[m][k] * Bt[n][k];  M=4096, N=1024, K=1024
// AF32: A is f32 (converted to bf16 during staging), else A is bf16.
// EPI 0: dst bf16 [b][h][s][hd]   (q / k)  (value scaled by ascale)
// EPI 1: dst bf16 [b][h][hd][s]   (v transposed)
// EPI 2: dst f32  [m][n] + bias[n] (final output)
// ---------------------------------------------------------------------------
template<bool AF32, int EPI>
__global__ __launch_bounds__(256)
void gemm_k(const void* __restrict__ Ap, const short* __restrict__ Bt,
            void* __restrict__ Cp, const float* __restrict__ bias, float ascale) {
  constexpr int K = 1024;
  __shared__ short As[128 * 32];
  __shared__ short Bs[128 * 32];
  const int tid = threadIdx.x;
  const int l = tid & 63;
  const int w = tid >> 6;
  const int wr = w >> 1, wc = w & 1;
  const int bid = blockIdx.x;
  const int bm = bid >> 3, bn = bid & 7;

  f32x4 acc[4][4] = {};
  const int c0 = tid * 2;

  for (int k0 = 0; k0 < K; k0 += 32) {
    __syncthreads();
    if (AF32) {
      const float* A = (const float*)Ap;
#pragma unroll
      for (int i = 0; i < 2; ++i) {
        int c = c0 + i;
        int row = c >> 2, ko = (c & 3) * 8;
        const float* src = A + (size_t)(bm * 128 + row) * K + k0 + ko;
        float4 f0 = *(const float4*)src;
        float4 f1 = *(const float4*)(src + 4);
        short8 v;
        v[0] = (short)f2bf(f0.x); v[1] = (short)f2bf(f0.y);
        v[2] = (short)f2bf(f0.z); v[3] = (short)f2bf(f0.w);
        v[4] = (short)f2bf(f1.x); v[5] = (short)f2bf(f1.y);
        v[6] = (short)f2bf(f1.z); v[7] = (short)f2bf(f1.w);
        *(short8*)&As[row * 32 + ko] = v;
      }
    } else {
      const short* A = (const short*)Ap;
#pragma unroll
      for (int i = 0; i < 2; ++i) {
        int c = c0 + i;
        int row = c >> 2, ko = (c & 3) * 8;
        *(short8*)&As[row * 32 + ko] =
            *(const short8*)(A + (size_t)(bm * 128 + row) * K + k0 + ko);
      }
    }
#pragma unroll
    for (int i = 0; i < 2; ++i) {
      int c = c0 + i;
      int row = c >> 2, ko = (c & 3) * 8;
      *(short8*)&Bs[row * 32 + ko] =
          *(const short8*)(Bt + (size_t)(bn * 128 + row) * K + k0 + ko);
    }
    __syncthreads();

    short8 af[4], bf[4];
#pragma unroll
    for (int mi = 0; mi < 4; ++mi)
      af[mi] = *(const short8*)&As[(wr * 64 + mi * 16 + (l & 15)) * 32 + (l >> 4) * 8];
#pragma unroll
    for (int ni = 0; ni < 4; ++ni)
      bf[ni] = *(const short8*)&Bs[(wc * 64 + ni * 16 + (l & 15)) * 32 + (l >> 4) * 8];
#pragma unroll
    for (int mi = 0; mi < 4; ++mi)
#pragma unroll
      for (int ni = 0; ni < 4; ++ni)
        acc[mi][ni] = __builtin_amdgcn_mfma_f32_16x16x32_bf16(af[mi], bf[ni], acc[mi][ni], 0, 0, 0);
  }

  const int mb = bm * 128 + wr * 64 + (l >> 4) * 4;
  const int nb = bn * 128 + wc * 64 + (l & 15);
#pragma unroll
  for (int mi = 0; mi < 4; ++mi) {
#pragma unroll
    for (int ni = 0; ni < 4; ++ni) {
#pragma unroll
      for (int j = 0; j < 4; ++j) {
        float v = acc[mi][ni][j] * ascale;
        int m = mb + mi * 16 + j;
        int n = nb + ni * 16;
        if (EPI == 2) {
          ((float*)Cp)[(size_t)m * 1024 + n] = v + bias[n];
        } else {
          int b = m >> 11, s = m & 2047, h = n >> 6, hd = n & 63;
          size_t idx;
          if (EPI == 0) idx = ((size_t)((b * 16 + h) * 2048 + s)) * 64 + hd;
          else          idx = ((size_t)((b * 16 + h) * 64 + hd)) * 2048 + s;
          ((unsigned short*)Cp)[idx] = f2bf(v);
        }
      }
    }
  }
}

// ---------------------------------------------------------------------------
// Flash attention v2: swapped QK^T (scores lane-local per query), KVBLK=64,
// exp2-domain (q pre-scaled), defer-max (THR=8), P via padded LDS (144B rows).
// block = (b,h,qtile of 64 rows), 4 waves x 16 rows.
// q/k: [b][h][s][64] bf16 (q pre-scaled); v: [b][h][64][s] bf16 (transposed).
// Output: attn concat layout [b][s][h*64+hd] bf16.
// ---------------------------------------------------------------------------
__global__ __launch_bounds__(256)
void attn_k(const unsigned short* __restrict__ qh, const unsigned short* __restrict__ kh,
            const unsigned short* __restrict__ vT, unsigned short* __restrict__ attnc) {
  __shared__ __attribute__((aligned(16))) short Pl[4][16 * 72];  // 144B row stride
  // XCD-aware swizzle (bijective: 1024 = 8*128): 32 q-tiles of 4 heads per XCD
  const int bid = (blockIdx.x & 7) * 128 + (blockIdx.x >> 3);
  const int qt = bid & 31;
  const int h = (bid >> 5) & 15;
  const int b = bid >> 9;
  const int tid = threadIdx.x;
  const int l = tid & 63;
  const int w = tid >> 6;
  const int lg = l >> 4;
  const int lc = l & 15;

  const unsigned short* qb = qh + (size_t)((b * 16 + h) * 2048) * 64;
  const unsigned short* kb = kh + (size_t)((b * 16 + h) * 2048) * 64;
  const unsigned short* vb = vT + (size_t)((b * 16 + h) * 64) * 2048;

  const int s0 = qt * 64 + w * 16;
  const short8 qf0 = *(const short8*)(qb + (s0 + lc) * 64 + lg * 8);
  const short8 qf1 = *(const short8*)(qb + (s0 + lc) * 64 + 32 + lg * 8);

  float m_r = -1e30f, l_r = 0.f;
  f32x4 acco[4] = {};
  short* pw = &Pl[w][0];
  const f32x4 zero = {0.f, 0.f, 0.f, 0.f};

  for (int t0 = 0; t0 < 2048; t0 += 64) {
    // K fragments: 4 subtiles of 16 keys
    short8 kf[4][2];
#pragma unroll
    for (int kk = 0; kk < 4; ++kk) {
      const unsigned short* kp = kb + (size_t)(t0 + kk * 16 + lc) * 64 + lg * 8;
      kf[kk][0] = *(const short8*)kp;
      kf[kk][1] = *(const short8*)(kp + 32);
    }
    // V fragments (independent of softmax; issue early)
    short8 vf[2][4];
#pragma unroll
    for (int hf = 0; hf < 2; ++hf)
#pragma unroll
      for (int n = 0; n < 4; ++n)
        vf[hf][n] = *(const short8*)(vb + (size_t)(n * 16 + lc) * 2048 + t0 + hf * 32 + lg * 8);

    // S^T = K·Q^T : lane holds 16 scores for query s0+lc (keys kk*16+lg*4+j)
    f32x4 s_[4];
#pragma unroll
    for (int kk = 0; kk < 4; ++kk) {
      s_[kk] = __builtin_amdgcn_mfma_f32_16x16x32_bf16(kf[kk][0], qf0, zero, 0, 0, 0);
      s_[kk] = __builtin_amdgcn_mfma_f32_16x16x32_bf16(kf[kk][1], qf1, s_[kk], 0, 0, 0);
    }

    // tile max: in-lane tree + 2 shfls
    float tmk[4];
#pragma unroll
    for (int kk = 0; kk < 4; ++kk)
      tmk[kk] = fmaxf(fmaxf(s_[kk][0], s_[kk][1]), fmaxf(s_[kk][2], s_[kk][3]));
    float tm = fmaxf(fmaxf(tmk[0], tmk[1]), fmaxf(tmk[2], tmk[3]));
    tm = fmaxf(tm, __shfl_xor(tm, 16));
    tm = fmaxf(tm, __shfl_xor(tm, 32));

    // defer-max: rescale only when some row's max grew by > 8 (exp2 domain)
    if (!__all(tm - m_r <= 8.0f)) {
      float mn = fmaxf(m_r, tm);
      float sc = exp2_fast(m_r - mn);
      m_r = mn;
      l_r *= sc;
      float scj[4];
#pragma unroll
      for (int j = 0; j < 4; ++j) scj[j] = __shfl(sc, lg * 4 + j);
#pragma unroll
      for (int n = 0; n < 4; ++n)
#pragma unroll
        for (int j = 0; j < 4; ++j) acco[n][j] *= scj[j];
    }

    // P = exp2(S - m), bf16, into per-wave LDS rows P[q=lc][key]
    float rs = 0.f;
#pragma unroll
    for (int kk = 0; kk < 4; ++kk) {
      short4v pk;
#pragma unroll
      for (int j = 0; j < 4; ++j) {
        float p = exp2_fast(s_[kk][j] - m_r);
        rs += p;
        pk[j] = (short)f2bf(p);
      }
      *(short4v*)&pw[lc * 72 + kk * 16 + lg * 4] = pk;
    }
    rs += __shfl_xor(rs, 16);
    rs += __shfl_xor(rs, 32);
    l_r += rs;

    // PV: A = P rows (q), B = V^T rows (d)
    short8 pf0 = *(const short8*)&pw[lc * 72 + lg * 8];
    short8 pf1 = *(const short8*)&pw[lc * 72 + 32 + lg * 8];
#pragma unroll
    for (int n = 0; n < 4; ++n)
      acco[n] = __builtin_amdgcn_mfma_f32_16x16x32_bf16(pf0, vf[0][n], acco[n], 0, 0, 0);
#pragma unroll
    for (int n = 0; n < 4; ++n)
      acco[n] = __builtin_amdgcn_mfma_f32_16x16x32_bf16(pf1, vf[1][n], acco[n], 0, 0, 0);
  }

  // normalize: l_r lives on lane with lc = q; acco rows are q = lg*4+j
  float inv = 1.0f / l_r;
  float invj[4];
#pragma unroll
  for (int j = 0; j < 4; ++j) invj[j] = __shfl(inv, lg * 4 + j);
#pragma unroll
  for (int n = 0; n < 4; ++n)
#pragma unroll
    for (int j = 0; j < 4; ++j) {
      int s = s0 + lg * 4 + j;
      int col = h * 64 + n * 16 + lc;
      attnc[(size_t)(b * 2048 + s) * 1024 + col] = f2bf(acco[n][j] * invj[j]);
    }
}

// ---------------------------------------------------------------------------
extern "C" void kernel_launch(void* const* d_in, const int* in_sizes, int n_in,
                              void* d_out, int out_size, void* d_ws, size_t ws_size,
                              hipStream_t stream) {
  const float* Q  = (const float*)d_in[0];
  const float* Kt = (const float*)d_in[1];
  const float* V  = (const float*)d_in[2];
  const float* Wq = (const float*)d_in[3];
  const float* Wv = (const float*)d_in[4];
  const float* Wo = (const float*)d_in[5];
  const float* bo = (const float*)d_in[6];
  float* out = (float*)d_out;

  char* ws = (char*)d_ws;
  unsigned short* qh   = (unsigned short*)(ws);                      // 8 MB
  unsigned short* kh   = (unsigned short*)(ws + ((size_t)8 << 20));  // 8 MB
  unsigned short* vTh  = (unsigned short*)(ws + ((size_t)16 << 20)); // 8 MB
  unsigned short* attc = (unsigned short*)(ws + ((size_t)24 << 20)); // 8 MB
  unsigned short* BqT  = (unsigned short*)(ws + ((size_t)32 << 20)); // 2 MB
  unsigned short* BvT  = (unsigned short*)(ws + ((size_t)34 << 20)); // 2 MB
  unsigned short* BoT  = (unsigned short*)(ws + ((size_t)36 << 20)); // 2 MB

  wtrans_k<<<256, 256, 0, stream>>>(Wq, BqT);
  wtrans_k<<<256, 256, 0, stream>>>(Wv, BvT);
  wo_conv_k<<<1024, 256, 0, stream>>>(Wo, BoT);

  // q carries 1/sqrt(HD) * log2(e) so attention works in exp2 domain
  gemm_k<true, 0><<<256, 256, 0, stream>>>(Q,  (const short*)BqT, qh, nullptr, QSCALE);
  gemm_k<true, 0><<<256, 256, 0, stream>>>(Kt, (const short*)BqT, kh, nullptr, 1.0f);
  gemm_k<true, 1><<<256, 256, 0, stream>>>(V,  (const short*)BvT, vTh, nullptr, 1.0f);

  attn_k<<<1024, 256, 0, stream>>>(qh, kh, vTh, attc);

  gemm_k<false, 2><<<256, 256, 0, stream>>>(attc, (const short*)BoT, out, bo, 1.0f);
}